// Round 2
// baseline (819.455 us; speedup 1.0000x reference)
//
#include <hip/hip_runtime.h>
#include <cstdint>
#include <cstddef>

#define TPB 256

// fc: feat0[n][b][c] = latents[b] . fc_W[:, n*64+c] + fc_b
__global__ __launch_bounds__(TPB) void k_fc(
    const float* __restrict__ lat, const float* __restrict__ W,
    const float* __restrict__ bias, float* __restrict__ out)
{
    int tid = blockIdx.x * TPB + threadIdx.x;   // 256*8*64 = 131072
    int c = tid & 63;
    int b = (tid >> 6) & 7;
    int n = tid >> 9;
    int j = n * 64 + c;
    float acc = bias[j];
    const float* lb = lat + b * 64;
#pragma unroll 16
    for (int l = 0; l < 64; ++l)
        acc = fmaf(lb[l], W[l * 16384 + j], acc);
    out[tid] = acc;
}

// Y[nb][co] = X[nb][:] . W[:][co]   (used for feat@W and Ub@W)
template<int CI, int CO>
__global__ __launch_bounds__(TPB) void k_matw(
    const float* __restrict__ X, const float* __restrict__ W,
    float* __restrict__ Y, int NB)
{
    int tid = blockIdx.x * TPB + threadIdx.x;
    if (tid >= NB * CO) return;
    int co = tid % CO;
    int nb = tid / CO;
    const float* x = X + (size_t)nb * CI;
    float acc = 0.f;
#pragma unroll
    for (int ci = 0; ci < CI; ++ci)
        acc = fmaf(x[ci], W[ci * CO + co], acc);
    Y[tid] = acc;
}

__global__ __launch_bounds__(TPB) void k_zero1(float* a, int na)
{
    int tid = blockIdx.x * TPB + threadIdx.x;
    if (tid < na) a[tid] = 0.f;
}

// Tiled GEMM: up[M][NTOT] = U[M][K] @ F[K][NTOT] + UbW[row][col % CO]
// Block tile: RT=32 rows x NT cols, K chunked by KC=128. No atomics.
// U staged in LDS with XOR quad-swizzle (bank-even b128 reads);
// F staged in k-quad layout [q][j][4] so inner loop reads are b128.
template<int K, int NTOT, int CO, int NT, int CPT>
__global__ __launch_bounds__(TPB) void k_gemm(
    const float* __restrict__ U, const float* __restrict__ F,
    const float* __restrict__ UbW, float* __restrict__ up)
{
    constexpr int RT = 32;
    constexpr int JG = TPB / RT;           // 8 col-groups
    constexpr int KC = 128;
    constexpr int QC = KC / 4;             // 32 quads per row-chunk
    static_assert(JG * CPT == NT, "col coverage");
    static_assert(K % KC == 0, "K chunking");

    __shared__ float u_lds[RT * KC];       // swizzled quads, 16 KB
    __shared__ float f_lds[QC * NT * 4];   // [q][j][i], <=16 KB

    const int tid = threadIdx.x;
    const int r  = tid % RT;
    const int jg = tid / RT;
    const int row0 = blockIdx.x * RT;
    const int jc   = blockIdx.y * NT;

    float acc[CPT];
#pragma unroll
    for (int c = 0; c < CPT; ++c) acc[c] = 0.f;

    for (int kc = 0; kc < K; kc += KC) {
        __syncthreads();
        // stage U tile: RT*QC quads, coalesced float4 global reads
#pragma unroll
        for (int l = tid; l < RT * QC; l += TPB) {
            int rr = l / QC, q = l % QC;
            float4 v = *reinterpret_cast<const float4*>(
                U + (size_t)(row0 + rr) * K + kc + 4 * q);
            int slot = q ^ (rr & 7);
            *reinterpret_cast<float4*>(u_lds + rr * KC + 4 * slot) = v;
        }
        // stage F chunk transposed to k-quad layout
#pragma unroll
        for (int l = tid; l < KC * NT; l += TPB) {
            int kk = l / NT, j = l % NT;
            f_lds[(kk >> 2) * (NT * 4) + j * 4 + (kk & 3)] =
                F[(size_t)(kc + kk) * NTOT + jc + j];
        }
        __syncthreads();
#pragma unroll 4
        for (int q = 0; q < QC; ++q) {
            float4 u = *reinterpret_cast<const float4*>(
                u_lds + r * KC + 4 * (q ^ (r & 7)));
            const float* fb = f_lds + q * (NT * 4) + (jg * CPT) * 4;
#pragma unroll
            for (int c = 0; c < CPT; ++c) {
                float4 f = *reinterpret_cast<const float4*>(fb + 4 * c);
                acc[c] = fmaf(u.x, f.x, acc[c]);
                acc[c] = fmaf(u.y, f.y, acc[c]);
                acc[c] = fmaf(u.z, f.z, acc[c]);
                acc[c] = fmaf(u.w, f.w, acc[c]);
            }
        }
    }
    const int row = row0 + r;
#pragma unroll
    for (int c = 0; c < CPT; ++c) {
        int col = jc + jg * CPT + c;
        up[(size_t)row * NTOT + col] =
            acc[c] + UbW[(size_t)row * CO + (col % CO)];
    }
}

// agg[rows[e]][j0..j0+3] += vals[e] * up[cols[e]][j0..j0+3]
template<int BC>
__global__ __launch_bounds__(TPB) void k_scatter4(
    const float* __restrict__ up, const int* __restrict__ rows,
    const int* __restrict__ cols, const float* __restrict__ vals,
    float* __restrict__ agg, int E)
{
    constexpr int JQ = BC / 4;
    int tid = blockIdx.x * TPB + threadIdx.x;
    if (tid >= E * JQ) return;
    int e = tid / JQ;
    int j0 = (tid % JQ) * 4;
    float v = vals[e];
    int c = cols[e], rr = rows[e];
    float4 u = *reinterpret_cast<const float4*>(&up[(size_t)c * BC + j0]);
    float* a = &agg[(size_t)rr * BC + j0];
    atomicAdd(a + 0, v * u.x);
    atomicAdd(a + 1, v * u.y);
    atomicAdd(a + 2, v * u.z);
    atomicAdd(a + 3, v * u.w);
}

template<int CO>
__global__ __launch_bounds__(TPB) void k_relu_bias(
    const float* __restrict__ agg, const float* __restrict__ bias,
    float* __restrict__ out, int n)
{
    int tid = blockIdx.x * TPB + threadIdx.x;
    if (tid >= n) return;
    float x = agg[tid] + bias[tid % CO];
    out[tid] = fmaxf(x, 0.f);
}

// out[b][n][j] = relu(agg[n][b*3+j] + bias[j]),  agg: [16384][24]
__global__ __launch_bounds__(TPB) void k_out(
    const float* __restrict__ agg, const float* __restrict__ bias,
    float* __restrict__ out)
{
    int tid = blockIdx.x * TPB + threadIdx.x;   // 393216
    int j = tid % 3;
    int n = (tid / 3) & 16383;
    int b = tid / 49152;
    float x = agg[(size_t)n * 24 + b * 3 + j] + bias[j];
    out[tid] = fmaxf(x, 0.f);
}

extern "C" void kernel_launch(void* const* d_in, const int* in_sizes, int n_in,
                              void* d_out, int out_size, void* d_ws, size_t ws_size,
                              hipStream_t stream)
{
    const float* lat   = (const float*)d_in[0];
    const float* fcW   = (const float*)d_in[1];
    const float* fcb   = (const float*)d_in[2];
    const float* U0    = (const float*)d_in[3];
    const float* Ub0   = (const float*)d_in[4];
    const float* W0    = (const float*)d_in[5];
    const float* b0    = (const float*)d_in[6];
    const float* vals0 = (const float*)d_in[7];
    const int*   rows0 = (const int*)d_in[8];
    const int*   cols0 = (const int*)d_in[9];
    const float* U1    = (const float*)d_in[10];
    const float* Ub1   = (const float*)d_in[11];
    const float* W1    = (const float*)d_in[12];
    const float* b1    = (const float*)d_in[13];
    const float* vals1 = (const float*)d_in[14];
    const int*   rows1 = (const int*)d_in[15];
    const int*   cols1 = (const int*)d_in[16];
    const float* U2    = (const float*)d_in[17];
    const float* Ub2   = (const float*)d_in[18];
    const float* W2    = (const float*)d_in[19];
    const float* b2    = (const float*)d_in[20];
    const float* vals2 = (const float*)d_in[21];
    const int*   rows2 = (const int*)d_in[22];
    const int*   cols2 = (const int*)d_in[23];

    float* ws    = (float*)d_ws;
    float* featA = ws;                  // 1048576 floats
    float* featB = featA + 1048576;     // 1048576
    float* fWb   = featB + 1048576;     // 262144
    float* UbWb  = fWb   + 262144;      // 131072
    float* up    = UbWb  + 131072;      // 1048576
    float* agg   = up    + 1048576;     // 1048576

    float* out = (float*)d_out;

    // fc -> featA = feat0 [256][8][64]
    hipLaunchKernelGGL(k_fc, dim3(131072 / TPB), dim3(TPB), 0, stream, lat, fcW, fcb, featA);

    // ---- layer 0: M=1024 K=256 BC=512 CO=64 ----
    hipLaunchKernelGGL((k_matw<64, 64>), dim3(131072 / TPB), dim3(TPB), 0, stream, featA, W0, fWb, 2048);
    hipLaunchKernelGGL((k_matw<64, 64>), dim3(65536 / TPB), dim3(TPB), 0, stream, Ub0, W0, UbWb, 1024);
    hipLaunchKernelGGL(k_zero1, dim3(524288 / TPB), dim3(TPB), 0, stream, agg, 524288);
    hipLaunchKernelGGL((k_gemm<256, 512, 64, 32, 4>), dim3(32, 16), dim3(TPB), 0, stream, U0, fWb, UbWb, up);
    hipLaunchKernelGGL((k_scatter4<512>), dim3(2097152 / TPB), dim3(TPB), 0, stream, up, rows0, cols0, vals0, agg, 16384);
    hipLaunchKernelGGL((k_relu_bias<64>), dim3(524288 / TPB), dim3(TPB), 0, stream, agg, b0, featB, 524288);

    // ---- layer 1: M=4096 K=1024 BC=256 CO=32 ----
    hipLaunchKernelGGL((k_matw<64, 32>), dim3(262144 / TPB), dim3(TPB), 0, stream, featB, W1, fWb, 8192);
    hipLaunchKernelGGL((k_matw<64, 32>), dim3(131072 / TPB), dim3(TPB), 0, stream, Ub1, W1, UbWb, 4096);
    hipLaunchKernelGGL(k_zero1, dim3(1048576 / TPB), dim3(TPB), 0, stream, agg, 1048576);
    hipLaunchKernelGGL((k_gemm<1024, 256, 32, 32, 4>), dim3(128, 8), dim3(TPB), 0, stream, U1, fWb, UbWb, up);
    hipLaunchKernelGGL((k_scatter4<256>), dim3(4194304 / TPB), dim3(TPB), 0, stream, up, rows1, cols1, vals1, agg, 65536);
    hipLaunchKernelGGL((k_relu_bias<32>), dim3(1048576 / TPB), dim3(TPB), 0, stream, agg, b1, featA, 1048576);

    // ---- layer 2: M=16384 K=4096 BC=24 CO=3 ----
    hipLaunchKernelGGL((k_matw<32, 3>), dim3((98304 + TPB - 1) / TPB), dim3(TPB), 0, stream, featA, W2, fWb, 32768);
    hipLaunchKernelGGL((k_matw<32, 3>), dim3((49152 + TPB - 1) / TPB), dim3(TPB), 0, stream, Ub2, W2, UbWb, 16384);
    hipLaunchKernelGGL(k_zero1, dim3(393216 / TPB), dim3(TPB), 0, stream, agg, 393216);
    hipLaunchKernelGGL((k_gemm<4096, 24, 3, 24, 3>), dim3(512, 1), dim3(TPB), 0, stream, U2, fWb, UbWb, up);
    hipLaunchKernelGGL((k_scatter4<24>), dim3((1572864 + TPB - 1) / TPB), dim3(TPB), 0, stream, up, rows2, cols2, vals2, agg, 262144);
    hipLaunchKernelGGL(k_out, dim3(393216 / TPB), dim3(TPB), 0, stream, agg, b2, out);
}